// Round 17
// baseline (217.438 us; speedup 1.0000x reference)
//
#include <hip/hip_runtime.h>
#include <stdint.h>

#define BR 262144
#define NTAB 17
#define MAXR 512
#define DIN 272
#define AS0 296   // LDS row stride (bf16) layer0 (K padded to 288); also C-restage stride
#define ASM 264   // LDS row stride (bf16) mid layers (K=256); also C-restage stride
#define NCOPY 64
#define BNEPS 1e-5f

typedef __attribute__((ext_vector_type(8))) short short8;
typedef __attribute__((ext_vector_type(4))) float f32x4;
typedef __attribute__((ext_vector_type(4))) unsigned short ushort4w;

__device__ __forceinline__ unsigned short f2bf(float f) {
  union { float f; unsigned u; } v; v.f = f;
  return (unsigned short)((v.u + 0x7FFFu + ((v.u >> 16) & 1u)) >> 16);
}
__device__ __forceinline__ float bf2f(unsigned short h) {
  union { unsigned u; float f; } v; v.u = ((unsigned)h) << 16;
  return v.f;
}

// ---------- prep: tables f32 -> bf16; pack W0 -> MFMA B-frags; zero stats ----------
__global__ void k_prep0(const float* __restrict__ W0, const float* __restrict__ tables,
                        unsigned short* __restrict__ pW0, unsigned short* __restrict__ tb,
                        float* __restrict__ stats) {
  int tid = blockIdx.x * blockDim.x + threadIdx.x;
  int nth = gridDim.x * blockDim.x;
  for (int i = tid; i < NCOPY * 1280; i += nth) stats[i] = 0.f;
  for (int e = tid; e < 17408; e += nth) {
    const float* src = tables + (size_t)e * 8;
    f32x4 v0 = ((const f32x4*)src)[0];
    f32x4 v1 = ((const f32x4*)src)[1];
    unsigned short tmp[8];
#pragma unroll
    for (int j = 0; j < 4; j++) { tmp[j] = f2bf(v0[j]); tmp[4 + j] = f2bf(v1[j]); }
    *(short8*)&tb[(size_t)e * 8] = *(short8*)tmp;
  }
  for (int e = tid; e < 9 * 16 * 64; e += nth) {
    int l = e & 63, f = e >> 6;
    int nf = f & 15, ks = f >> 4;
    int col = nf * 16 + (l & 15);
    int kb = ks * 32 + ((l >> 4) << 3);
    unsigned short tmp[8];
#pragma unroll
    for (int j = 0; j < 8; j++) {
      int k = kb + j;
      tmp[j] = f2bf(k < DIN ? W0[k * 256 + col] : 0.f);
    }
    *(short8*)&pW0[(size_t)e * 8] = *(short8*)tmp;
  }
}

// ---------- fold BN(layer l) into W(l+1) ----------
template <int KP, int NP>
__global__ void k_fold(const float* __restrict__ stats, int offSum, int offSq,
                       const float* __restrict__ g, const float* __restrict__ be,
                       const float* __restrict__ W, const float* __restrict__ b,
                       unsigned short* __restrict__ pW, float* __restrict__ bOut) {
  __shared__ float sa[KP], sc[KP];
  int tid = threadIdx.x;  // 256
  if (tid < KP) {
    float s = 0.f, q = 0.f;
    for (int c = 0; c < NCOPY; c++) {
      s += stats[c * 1280 + offSum + tid];
      q += stats[c * 1280 + offSq + tid];
    }
    float mu = s * (1.f / BR);
    float var = fmaxf(q * (1.f / BR) - mu * mu, 0.f);
    float a = g[tid] * rsqrtf(var + BNEPS);
    sa[tid] = a;
    sc[tid] = be[tid] - mu * a;
  }
  __syncthreads();
  const int NFT = NP / 16;
  const int ENT = (KP / 32) * NFT * 64;
  for (int e = blockIdx.x * blockDim.x + tid; e < ENT; e += gridDim.x * blockDim.x) {
    int l = e & 63, f = e >> 6;
    int nf = f % NFT, ks = f / NFT;
    int col = nf * 16 + (l & 15);
    int kb = ks * 32 + ((l >> 4) << 3);
    unsigned short tmp[8];
#pragma unroll
    for (int j = 0; j < 8; j++) {
      int k = kb + j;
      tmp[j] = f2bf(sa[k] * W[k * NP + col]);
    }
    *(short8*)&pW[(size_t)e * 8] = *(short8*)tmp;
  }
  if (blockIdx.x == 0 && tid < NP) {
    float s = b[tid];
    for (int k = 0; k < KP; k++) s += sc[k] * W[k * NP + tid];
    bOut[tid] = s;
  }
}

// ---------- fold BN(layer2) into Wout ----------
__global__ void k_foldout(const float* __restrict__ stats, int offSum, int offSq,
                          const float* __restrict__ g, const float* __restrict__ be,
                          const float* __restrict__ Wout, const float* __restrict__ bout,
                          float* __restrict__ woutp, float* __restrict__ boutp) {
  __shared__ float red[128];
  int tid = threadIdx.x;  // 128 threads
  float s = 0.f, q = 0.f;
  for (int c = 0; c < NCOPY; c++) {
    s += stats[c * 1280 + offSum + tid];
    q += stats[c * 1280 + offSq + tid];
  }
  float mu = s * (1.f / BR);
  float var = fmaxf(q * (1.f / BR) - mu * mu, 0.f);
  float a = g[tid] * rsqrtf(var + BNEPS);
  float c = be[tid] - mu * a;
  float w = Wout[tid];
  woutp[tid] = a * w;
  red[tid] = c * w;
  __syncthreads();
  for (int st = 64; st > 0; st >>= 1) {
    if (tid < st) red[tid] += red[tid + st];
    __syncthreads();
  }
  if (tid == 0) boutp[0] = red[0] + bout[0];
}

// ---------- shared GEMM body (R12 structure; stats scratch overlaid on As) ----------
// swapped-operand MFMA acc frag: row = lane&15, col = (lane>>4)*4 + j  (verified R1-R16)
template <int KSTEPS, int N, int AST, int MF>
__device__ __forceinline__ void gemm_body(unsigned short* As,
                                          const unsigned short* __restrict__ pW,
                                          const float* __restrict__ bias, unsigned short* __restrict__ Y,
                                          int bid, float* __restrict__ stats, int offSum, int offSq) {
  const int tid = threadIdx.x;
  const int lane = tid & 63, wave = tid >> 6;
  constexpr int WC = N / 64;
  constexpr int CH = N / 8;
  const int wc = wave % WC, wr = wave / WC;
  const int wrow = wr * (MF * 16);
  const int wcolf = wc * 4;
  const int arow = lane & 15;
  const int koff = (lane >> 4) << 3;
  const int grp = lane >> 4;
  const int brow = bid * 64;

  f32x4 zero4 = {0.f, 0.f, 0.f, 0.f};
  f32x4 acc[MF][4];
#pragma unroll
  for (int mf = 0; mf < MF; mf++)
#pragma unroll
    for (int nf = 0; nf < 4; nf++) acc[mf][nf] = zero4;

  short8 bcur[4], bnxt[4];
#pragma unroll
  for (int nf = 0; nf < 4; nf++)
    bcur[nf] = *(const short8*)&pW[(size_t)((wcolf + nf) * 64 + lane) * 8];

#pragma unroll
  for (int ks = 0; ks < KSTEPS; ks++) {
    if (ks + 1 < KSTEPS) {
#pragma unroll
      for (int nf = 0; nf < 4; nf++)
        bnxt[nf] = *(const short8*)&pW[(size_t)(((ks + 1) * (N / 16) + wcolf + nf) * 64 + lane) * 8];
    }
#pragma unroll
    for (int mf = 0; mf < MF; mf++) {
      short8 am = *(const short8*)&As[(wrow + mf * 16 + arow) * AST + ks * 32 + koff];
#pragma unroll
      for (int nf = 0; nf < 4; nf++)
        acc[mf][nf] = __builtin_amdgcn_mfma_f32_16x16x32_bf16(bcur[nf], am, acc[mf][nf], 0, 0, 0);
    }
#pragma unroll
    for (int nf = 0; nf < 4; nf++) bcur[nf] = bnxt[nf];
  }

  __syncthreads();  // all As reads done; reuse As as C restage buffer (stride AST)

  // epilogue: bias + relu + bf16 restage to LDS (no stats here)
#pragma unroll
  for (int nf = 0; nf < 4; nf++) {
    const int c0 = (wcolf + nf) * 16 + grp * 4;
    f32x4 bb = *(const f32x4*)&bias[c0];
#pragma unroll
    for (int mf = 0; mf < MF; mf++) {
      const int r = wrow + mf * 16 + arow;
      unsigned short o[4];
#pragma unroll
      for (int j = 0; j < 4; j++) o[j] = f2bf(fmaxf(acc[mf][nf][j] + bb[j], 0.f));
      *(ushort4w*)&As[r * AST + c0] = *(ushort4w*)o;
    }
  }
  __syncthreads();

  // store phase: coalesced row-major Y store (16B/lane) + per-thread column stats
  float s8[8] = {0.f, 0.f, 0.f, 0.f, 0.f, 0.f, 0.f, 0.f};
  float q8[8] = {0.f, 0.f, 0.f, 0.f, 0.f, 0.f, 0.f, 0.f};
  const int ch = tid % CH;
#pragma unroll
  for (int k = 0; k < (64 * CH) / 256; k++) {
    int i = tid + k * 256;
    int row = i / CH;
    short8 v = *(const short8*)&As[row * AST + ch * 8];
    *(short8*)&Y[(size_t)(brow + row) * 256 + ch * 8] = v;
#pragma unroll
    for (int j = 0; j < 8; j++) {
      float f = bf2f((unsigned short)v[j]);
      s8[j] += f;
      q8[j] += f * f;
    }
  }
#pragma unroll
  for (int d = CH; d < 64; d <<= 1) {
#pragma unroll
    for (int j = 0; j < 8; j++) {
      s8[j] += __shfl_xor(s8[j], d, 64);
      q8[j] += __shfl_xor(q8[j], d, 64);
    }
  }
  __syncthreads();  // all As reads complete; overlay As as f32 stats scratch
  float* fbuf = (float*)As;  // [4 waves][CH][16] floats (<= As size)
  if (lane < CH) {
    float* dst = &fbuf[(wave * CH + lane) * 16];
#pragma unroll
    for (int j = 0; j < 8; j++) { dst[j] = s8[j]; dst[8 + j] = q8[j]; }
  }
  __syncthreads();
  float* gsum = stats + (size_t)(bid & (NCOPY - 1)) * 1280 + offSum;
  float* gsq  = stats + (size_t)(bid & (NCOPY - 1)) * 1280 + offSq;
  for (int o = tid; o < CH * 16; o += 256) {
    int c = o >> 4, v = o & 15;
    float t = fbuf[(0 * CH + c) * 16 + v] + fbuf[(1 * CH + c) * 16 + v] +
              fbuf[(2 * CH + c) * 16 + v] + fbuf[(3 * CH + c) * 16 + v];
    int col = c * 8 + (v & 7);
    atomicAdd((v < 8 ? gsum : gsq) + col, t);
  }
}

// ---------- layer 0: gather (idx-prefetch, 1 idx per (row,table)) + GEMM ----------
__global__ __launch_bounds__(256, 3) void k_gemm0(const int* __restrict__ x, const unsigned short* __restrict__ tb,
                        const unsigned short* __restrict__ pW, const float* __restrict__ bias,
                        unsigned short* __restrict__ Y, float* __restrict__ stats, int offSum, int offSq) {
  __shared__ unsigned short As[64 * AS0];
  const int tid = threadIdx.x;
  const int brow = blockIdx.x * 64;

  // phase 1: issue all idx loads (registers, static indices)
  int idxr[5];
#pragma unroll
  for (int j = 0; j < 5; j++) {
    int task = tid + j * 256;          // task = r*17 + t; 1088 tasks
    if (task < 64 * NTAB) {
      int r = task / NTAB;
      int t = task - r * NTAB;
      idxr[j] = x[(brow + r) * NTAB + t];
    }
  }
  // phase 2: zero K padding cols 272..295 (hides idx latency)
  short8 z8 = {0, 0, 0, 0, 0, 0, 0, 0};
  for (int t = tid; t < 64; t += 256) {
    *(short8*)&As[t * AS0 + 272] = z8;
    *(short8*)&As[t * AS0 + 280] = z8;
    *(short8*)&As[t * AS0 + 288] = z8;
  }
  // phase 3: gather 32B per task (2x16B loads + 2x16B LDS writes)
#pragma unroll
  for (int j = 0; j < 5; j++) {
    int task = tid + j * 256;
    if (task < 64 * NTAB) {
      int r = task / NTAB;
      int t = task - r * NTAB;
      const unsigned short* src = &tb[((size_t)(t * MAXR) + idxr[j]) * 16];
      short8 v0 = *(const short8*)src;
      short8 v1 = *(const short8*)(src + 8);
      unsigned base = r * AS0 + t * 16;
      *(short8*)&As[base] = v0;
      *(short8*)&As[base + 8] = v1;
    }
  }
  __syncthreads();
  gemm_body<9, 256, AS0, 4>(As, pW, bias, Y, blockIdx.x, stats, offSum, offSq);
}

// ---------- mid layers ----------
template <int N, int MF>
__global__ __launch_bounds__(256, 3) void k_gemm_mid(const unsigned short* __restrict__ Yin,
                           const unsigned short* __restrict__ pW, const float* __restrict__ bias,
                           unsigned short* __restrict__ Y, float* __restrict__ stats, int offSum, int offSq) {
  __shared__ unsigned short As[64 * ASM];
  const int tid = threadIdx.x;
  const int brow = blockIdx.x * 64;
  for (int i = tid; i < 64 * 32; i += 256) {
    int row = i >> 5, c16 = i & 31;
    short8 v = *(const short8*)&Yin[((size_t)(brow + row)) * 256 + c16 * 8];
    *(short8*)&As[row * ASM + c16 * 8] = v;
  }
  __syncthreads();
  gemm_body<8, N, ASM, MF>(As, pW, bias, Y, blockIdx.x, stats, offSum, offSq);
}

// ---------- final dot (R11 exact) ----------
__global__ void k_out(const unsigned short* __restrict__ Y, const float* __restrict__ woutp,
                      const float* __restrict__ boutp, float* __restrict__ out) {
  __shared__ float w[128];
  const int tid = threadIdx.x;
  if (tid < 128) w[tid] = woutp[tid];
  __syncthreads();
  const int lane = tid & 63, wave = tid >> 6;
  const int sub = lane & 7, rloc = lane >> 3;
  const int row = blockIdx.x * 32 + wave * 8 + rloc;
  const unsigned short* yr = &Y[(size_t)row * 256 + sub * 16];
  short8 v0 = *(const short8*)yr;
  short8 v1 = *(const short8*)(yr + 8);
  float acc = 0.f;
#pragma unroll
  for (int j = 0; j < 8; j++) acc += bf2f((unsigned short)v0[j]) * w[sub * 16 + j];
#pragma unroll
  for (int j = 0; j < 8; j++) acc += bf2f((unsigned short)v1[j]) * w[sub * 16 + 8 + j];
  acc += __shfl_xor(acc, 1, 64);
  acc += __shfl_xor(acc, 2, 64);
  acc += __shfl_xor(acc, 4, 64);
  if (sub == 0) out[row] = acc + boutp[0];
}

extern "C" void kernel_launch(void* const* d_in, const int* in_sizes, int n_in,
                              void* d_out, int out_size, void* d_ws, size_t ws_size,
                              hipStream_t stream) {
  const int* x = (const int*)d_in[0];
  const float* tables = (const float*)d_in[1];
  const float* W0 = (const float*)d_in[2];
  const float* b0 = (const float*)d_in[3];
  const float* g0 = (const float*)d_in[4];
  const float* be0 = (const float*)d_in[5];
  const float* W1 = (const float*)d_in[6];
  const float* b1 = (const float*)d_in[7];
  const float* g1 = (const float*)d_in[8];
  const float* be1 = (const float*)d_in[9];
  const float* W2 = (const float*)d_in[10];
  const float* b2 = (const float*)d_in[11];
  const float* g2 = (const float*)d_in[12];
  const float* be2 = (const float*)d_in[13];
  const float* Wout = (const float*)d_in[14];
  const float* bout = (const float*)d_in[15];
  float* out = (float*)d_out;

  char* ws = (char*)d_ws;
  unsigned short* Y = (unsigned short*)ws;
  size_t off = (size_t)BR * 256 * 2;  // 134,217,728
  unsigned short* pW0 = (unsigned short*)(ws + off); off += (size_t)9 * 16 * 64 * 8 * 2;
  unsigned short* pW1 = (unsigned short*)(ws + off); off += (size_t)8 * 16 * 64 * 8 * 2;
  unsigned short* pW2 = (unsigned short*)(ws + off); off += (size_t)8 * 8 * 64 * 8 * 2;
  float* b1p = (float*)(ws + off); off += 1024;
  float* b2p = (float*)(ws + off); off += 512;
  float* woutp = (float*)(ws + off); off += 512;
  float* boutp = (float*)(ws + off); off += 256;
  float* stats = (float*)(ws + off); off += (size_t)NCOPY * 1280 * 4;
  unsigned short* tb = (unsigned short*)(ws + off); off += (size_t)17 * MAXR * 16 * 2;

  const int oS0 = 0, oQ0 = 256, oS1 = 512, oQ1 = 768, oS2 = 1024, oQ2 = 1152;

  k_prep0<<<64, 256, 0, stream>>>(W0, tables, pW0, tb, stats);
  k_gemm0<<<BR / 64, 256, 0, stream>>>(x, tb, pW0, b0, Y, stats, oS0, oQ0);
  k_fold<256, 256><<<32, 256, 0, stream>>>(stats, oS0, oQ0, g0, be0, W1, b1, pW1, b1p);
  k_gemm_mid<256, 4><<<BR / 64, 256, 0, stream>>>(Y, pW1, b1p, Y, stats, oS1, oQ1);
  k_fold<256, 128><<<32, 256, 0, stream>>>(stats, oS1, oQ1, g1, be1, W2, b2, pW2, b2p);
  k_gemm_mid<128, 2><<<BR / 64, 256, 0, stream>>>(Y, pW2, b2p, Y, stats, oS2, oQ2);
  k_foldout<<<1, 128, 0, stream>>>(stats, oS2, oQ2, g2, be2, Wout, bout, woutp, boutp);
  k_out<<<BR / 32, 256, 0, stream>>>(Y, woutp, boutp, out);
}

// Round 18
// 212.618 us; speedup vs baseline: 1.0227x; 1.0227x over previous
//
#include <hip/hip_runtime.h>
#include <stdint.h>

#define BR 262144
#define NTAB 17
#define MAXR 512
#define DIN 272
#define AS0 296   // LDS row stride (bf16) layer0 (K padded to 288); also C-restage stride
#define ASM 264   // LDS row stride (bf16) mid layers (K=256); also C-restage stride
#define NCOPY 32
#define BNEPS 1e-5f

typedef __attribute__((ext_vector_type(8))) short short8;
typedef __attribute__((ext_vector_type(4))) float f32x4;
typedef __attribute__((ext_vector_type(4))) unsigned short ushort4w;

__device__ __forceinline__ unsigned short f2bf(float f) {
  union { float f; unsigned u; } v; v.f = f;
  return (unsigned short)((v.u + 0x7FFFu + ((v.u >> 16) & 1u)) >> 16);
}
__device__ __forceinline__ float bf2f(unsigned short h) {
  union { unsigned u; float f; } v; v.u = ((unsigned)h) << 16;
  return v.f;
}

// ---------- prep: tables f32 -> bf16; pack W0 -> MFMA B-frags; zero stats ----------
__global__ void k_prep0(const float* __restrict__ W0, const float* __restrict__ tables,
                        unsigned short* __restrict__ pW0, unsigned short* __restrict__ tb,
                        float* __restrict__ stats) {
  int tid = blockIdx.x * blockDim.x + threadIdx.x;
  int nth = gridDim.x * blockDim.x;
  for (int i = tid; i < NCOPY * 1280; i += nth) stats[i] = 0.f;
  for (int e = tid; e < 17408; e += nth) {
    const float* src = tables + (size_t)e * 8;
    f32x4 v0 = ((const f32x4*)src)[0];
    f32x4 v1 = ((const f32x4*)src)[1];
    unsigned short tmp[8];
#pragma unroll
    for (int j = 0; j < 4; j++) { tmp[j] = f2bf(v0[j]); tmp[4 + j] = f2bf(v1[j]); }
    *(short8*)&tb[(size_t)e * 8] = *(short8*)tmp;
  }
  for (int e = tid; e < 9 * 16 * 64; e += nth) {
    int l = e & 63, f = e >> 6;
    int nf = f & 15, ks = f >> 4;
    int col = nf * 16 + (l & 15);
    int kb = ks * 32 + ((l >> 4) << 3);
    unsigned short tmp[8];
#pragma unroll
    for (int j = 0; j < 8; j++) {
      int k = kb + j;
      tmp[j] = f2bf(k < DIN ? W0[k * 256 + col] : 0.f);
    }
    *(short8*)&pW0[(size_t)e * 8] = *(short8*)tmp;
  }
}

// ---------- fold BN(layer l) into W(l+1) ----------
template <int KP, int NP>
__global__ void k_fold(const float* __restrict__ stats, int offSum, int offSq,
                       const float* __restrict__ g, const float* __restrict__ be,
                       const float* __restrict__ W, const float* __restrict__ b,
                       unsigned short* __restrict__ pW, float* __restrict__ bOut) {
  __shared__ float sa[KP], sc[KP];
  int tid = threadIdx.x;  // 256
  if (tid < KP) {
    float s = 0.f, q = 0.f;
    for (int c = 0; c < NCOPY; c++) {
      s += stats[c * 1280 + offSum + tid];
      q += stats[c * 1280 + offSq + tid];
    }
    float mu = s * (1.f / BR);
    float var = fmaxf(q * (1.f / BR) - mu * mu, 0.f);
    float a = g[tid] * rsqrtf(var + BNEPS);
    sa[tid] = a;
    sc[tid] = be[tid] - mu * a;
  }
  __syncthreads();
  const int NFT = NP / 16;
  const int ENT = (KP / 32) * NFT * 64;
  for (int e = blockIdx.x * blockDim.x + tid; e < ENT; e += gridDim.x * blockDim.x) {
    int l = e & 63, f = e >> 6;
    int nf = f % NFT, ks = f / NFT;
    int col = nf * 16 + (l & 15);
    int kb = ks * 32 + ((l >> 4) << 3);
    unsigned short tmp[8];
#pragma unroll
    for (int j = 0; j < 8; j++) {
      int k = kb + j;
      tmp[j] = f2bf(sa[k] * W[k * NP + col]);
    }
    *(short8*)&pW[(size_t)e * 8] = *(short8*)tmp;
  }
  if (blockIdx.x == 0 && tid < NP) {
    float s = b[tid];
    for (int k = 0; k < KP; k++) s += sc[k] * W[k * NP + tid];
    bOut[tid] = s;
  }
}

// ---------- fold BN(layer2) into Wout ----------
__global__ void k_foldout(const float* __restrict__ stats, int offSum, int offSq,
                          const float* __restrict__ g, const float* __restrict__ be,
                          const float* __restrict__ Wout, const float* __restrict__ bout,
                          float* __restrict__ woutp, float* __restrict__ boutp) {
  __shared__ float red[128];
  int tid = threadIdx.x;  // 128 threads
  float s = 0.f, q = 0.f;
  for (int c = 0; c < NCOPY; c++) {
    s += stats[c * 1280 + offSum + tid];
    q += stats[c * 1280 + offSq + tid];
  }
  float mu = s * (1.f / BR);
  float var = fmaxf(q * (1.f / BR) - mu * mu, 0.f);
  float a = g[tid] * rsqrtf(var + BNEPS);
  float c = be[tid] - mu * a;
  float w = Wout[tid];
  woutp[tid] = a * w;
  red[tid] = c * w;
  __syncthreads();
  for (int st = 64; st > 0; st >>= 1) {
    if (tid < st) red[tid] += red[tid + st];
    __syncthreads();
  }
  if (tid == 0) boutp[0] = red[0] + bout[0];
}

// ---------- shared GEMM body (converged: stats in store phase, scratch overlaid on As) ----------
// swapped-operand MFMA acc frag: row = lane&15, col = (lane>>4)*4 + j  (verified R1-R17)
template <int KSTEPS, int N, int AST, int MF>
__device__ __forceinline__ void gemm_body(unsigned short* As,
                                          const unsigned short* __restrict__ pW,
                                          const float* __restrict__ bias, unsigned short* __restrict__ Y,
                                          int bid, float* __restrict__ stats, int offSum, int offSq) {
  const int tid = threadIdx.x;
  const int lane = tid & 63, wave = tid >> 6;
  constexpr int WC = N / 64;
  constexpr int CH = N / 8;
  const int wc = wave % WC, wr = wave / WC;
  const int wrow = wr * (MF * 16);
  const int wcolf = wc * 4;
  const int arow = lane & 15;
  const int koff = (lane >> 4) << 3;
  const int grp = lane >> 4;
  const int brow = bid * 64;

  f32x4 zero4 = {0.f, 0.f, 0.f, 0.f};
  f32x4 acc[MF][4];
#pragma unroll
  for (int mf = 0; mf < MF; mf++)
#pragma unroll
    for (int nf = 0; nf < 4; nf++) acc[mf][nf] = zero4;

  short8 bcur[4], bnxt[4];
#pragma unroll
  for (int nf = 0; nf < 4; nf++)
    bcur[nf] = *(const short8*)&pW[(size_t)((wcolf + nf) * 64 + lane) * 8];

#pragma unroll
  for (int ks = 0; ks < KSTEPS; ks++) {
    if (ks + 1 < KSTEPS) {
#pragma unroll
      for (int nf = 0; nf < 4; nf++)
        bnxt[nf] = *(const short8*)&pW[(size_t)(((ks + 1) * (N / 16) + wcolf + nf) * 64 + lane) * 8];
    }
#pragma unroll
    for (int mf = 0; mf < MF; mf++) {
      short8 am = *(const short8*)&As[(wrow + mf * 16 + arow) * AST + ks * 32 + koff];
#pragma unroll
      for (int nf = 0; nf < 4; nf++)
        acc[mf][nf] = __builtin_amdgcn_mfma_f32_16x16x32_bf16(bcur[nf], am, acc[mf][nf], 0, 0, 0);
    }
#pragma unroll
    for (int nf = 0; nf < 4; nf++) bcur[nf] = bnxt[nf];
  }

  __syncthreads();  // all As reads done; reuse As as C restage buffer (stride AST)

  // epilogue: bias + relu + bf16 restage to LDS (no stats here)
#pragma unroll
  for (int nf = 0; nf < 4; nf++) {
    const int c0 = (wcolf + nf) * 16 + grp * 4;
    f32x4 bb = *(const f32x4*)&bias[c0];
#pragma unroll
    for (int mf = 0; mf < MF; mf++) {
      const int r = wrow + mf * 16 + arow;
      unsigned short o[4];
#pragma unroll
      for (int j = 0; j < 4; j++) o[j] = f2bf(fmaxf(acc[mf][nf][j] + bb[j], 0.f));
      *(ushort4w*)&As[r * AST + c0] = *(ushort4w*)o;
    }
  }
  __syncthreads();

  // store phase: coalesced row-major Y store (16B/lane) + per-thread column stats
  float s8[8] = {0.f, 0.f, 0.f, 0.f, 0.f, 0.f, 0.f, 0.f};
  float q8[8] = {0.f, 0.f, 0.f, 0.f, 0.f, 0.f, 0.f, 0.f};
  const int ch = tid % CH;
#pragma unroll
  for (int k = 0; k < (64 * CH) / 256; k++) {
    int i = tid + k * 256;
    int row = i / CH;
    short8 v = *(const short8*)&As[row * AST + ch * 8];
    *(short8*)&Y[(size_t)(brow + row) * 256 + ch * 8] = v;
#pragma unroll
    for (int j = 0; j < 8; j++) {
      float f = bf2f((unsigned short)v[j]);
      s8[j] += f;
      q8[j] += f * f;
    }
  }
#pragma unroll
  for (int d = CH; d < 64; d <<= 1) {
#pragma unroll
    for (int j = 0; j < 8; j++) {
      s8[j] += __shfl_xor(s8[j], d, 64);
      q8[j] += __shfl_xor(q8[j], d, 64);
    }
  }
  __syncthreads();  // all As reads complete; overlay As as f32 stats scratch
  float* fbuf = (float*)As;  // [4 waves][CH][16] floats (<= As size)
  if (lane < CH) {
    float* dst = &fbuf[(wave * CH + lane) * 16];
#pragma unroll
    for (int j = 0; j < 8; j++) { dst[j] = s8[j]; dst[8 + j] = q8[j]; }
  }
  __syncthreads();
  float* gsum = stats + (size_t)(bid & (NCOPY - 1)) * 1280 + offSum;
  float* gsq  = stats + (size_t)(bid & (NCOPY - 1)) * 1280 + offSq;
  for (int o = tid; o < CH * 16; o += 256) {
    int c = o >> 4, v = o & 15;
    float t = fbuf[(0 * CH + c) * 16 + v] + fbuf[(1 * CH + c) * 16 + v] +
              fbuf[(2 * CH + c) * 16 + v] + fbuf[(3 * CH + c) * 16 + v];
    int col = c * 8 + (v & 7);
    atomicAdd((v < 8 ? gsum : gsq) + col, t);
  }
}

// ---------- layer 0: gather (idx-prefetch, 1 idx per (row,table)) + GEMM ----------
__global__ __launch_bounds__(256, 3) void k_gemm0(const int* __restrict__ x, const unsigned short* __restrict__ tb,
                        const unsigned short* __restrict__ pW, const float* __restrict__ bias,
                        unsigned short* __restrict__ Y, float* __restrict__ stats, int offSum, int offSq) {
  __shared__ unsigned short As[64 * AS0];
  const int tid = threadIdx.x;
  const int brow = blockIdx.x * 64;

  // phase 1: issue all idx loads (registers, static indices)
  int idxr[5];
#pragma unroll
  for (int j = 0; j < 5; j++) {
    int task = tid + j * 256;          // task = r*17 + t; 1088 tasks
    if (task < 64 * NTAB) {
      int r = task / NTAB;
      int t = task - r * NTAB;
      idxr[j] = x[(brow + r) * NTAB + t];
    }
  }
  // phase 2: zero K padding cols 272..295 (hides idx latency)
  short8 z8 = {0, 0, 0, 0, 0, 0, 0, 0};
  for (int t = tid; t < 64; t += 256) {
    *(short8*)&As[t * AS0 + 272] = z8;
    *(short8*)&As[t * AS0 + 280] = z8;
    *(short8*)&As[t * AS0 + 288] = z8;
  }
  // phase 3: gather 32B per task (2x16B loads + 2x16B LDS writes)
#pragma unroll
  for (int j = 0; j < 5; j++) {
    int task = tid + j * 256;
    if (task < 64 * NTAB) {
      int r = task / NTAB;
      int t = task - r * NTAB;
      const unsigned short* src = &tb[((size_t)(t * MAXR) + idxr[j]) * 16];
      short8 v0 = *(const short8*)src;
      short8 v1 = *(const short8*)(src + 8);
      unsigned base = r * AS0 + t * 16;
      *(short8*)&As[base] = v0;
      *(short8*)&As[base + 8] = v1;
    }
  }
  __syncthreads();
  gemm_body<9, 256, AS0, 4>(As, pW, bias, Y, blockIdx.x, stats, offSum, offSq);
}

// ---------- mid layers ----------
template <int N, int MF>
__global__ __launch_bounds__(256, 3) void k_gemm_mid(const unsigned short* __restrict__ Yin,
                           const unsigned short* __restrict__ pW, const float* __restrict__ bias,
                           unsigned short* __restrict__ Y, float* __restrict__ stats, int offSum, int offSq) {
  __shared__ unsigned short As[64 * ASM];
  const int tid = threadIdx.x;
  const int brow = blockIdx.x * 64;
  for (int i = tid; i < 64 * 32; i += 256) {
    int row = i >> 5, c16 = i & 31;
    short8 v = *(const short8*)&Yin[((size_t)(brow + row)) * 256 + c16 * 8];
    *(short8*)&As[row * ASM + c16 * 8] = v;
  }
  __syncthreads();
  gemm_body<8, N, ASM, MF>(As, pW, bias, Y, blockIdx.x, stats, offSum, offSq);
}

// ---------- final dot ----------
__global__ void k_out(const unsigned short* __restrict__ Y, const float* __restrict__ woutp,
                      const float* __restrict__ boutp, float* __restrict__ out) {
  __shared__ float w[128];
  const int tid = threadIdx.x;
  if (tid < 128) w[tid] = woutp[tid];
  __syncthreads();
  const int lane = tid & 63, wave = tid >> 6;
  const int sub = lane & 7, rloc = lane >> 3;
  const int row = blockIdx.x * 32 + wave * 8 + rloc;
  const unsigned short* yr = &Y[(size_t)row * 256 + sub * 16];
  short8 v0 = *(const short8*)yr;
  short8 v1 = *(const short8*)(yr + 8);
  float acc = 0.f;
#pragma unroll
  for (int j = 0; j < 8; j++) acc += bf2f((unsigned short)v0[j]) * w[sub * 16 + j];
#pragma unroll
  for (int j = 0; j < 8; j++) acc += bf2f((unsigned short)v1[j]) * w[sub * 16 + 8 + j];
  acc += __shfl_xor(acc, 1, 64);
  acc += __shfl_xor(acc, 2, 64);
  acc += __shfl_xor(acc, 4, 64);
  if (sub == 0) out[row] = acc + boutp[0];
}

extern "C" void kernel_launch(void* const* d_in, const int* in_sizes, int n_in,
                              void* d_out, int out_size, void* d_ws, size_t ws_size,
                              hipStream_t stream) {
  const int* x = (const int*)d_in[0];
  const float* tables = (const float*)d_in[1];
  const float* W0 = (const float*)d_in[2];
  const float* b0 = (const float*)d_in[3];
  const float* g0 = (const float*)d_in[4];
  const float* be0 = (const float*)d_in[5];
  const float* W1 = (const float*)d_in[6];
  const float* b1 = (const float*)d_in[7];
  const float* g1 = (const float*)d_in[8];
  const float* be1 = (const float*)d_in[9];
  const float* W2 = (const float*)d_in[10];
  const float* b2 = (const float*)d_in[11];
  const float* g2 = (const float*)d_in[12];
  const float* be2 = (const float*)d_in[13];
  const float* Wout = (const float*)d_in[14];
  const float* bout = (const float*)d_in[15];
  float* out = (float*)d_out;

  char* ws = (char*)d_ws;
  unsigned short* Y = (unsigned short*)ws;
  size_t off = (size_t)BR * 256 * 2;  // 134,217,728
  unsigned short* pW0 = (unsigned short*)(ws + off); off += (size_t)9 * 16 * 64 * 8 * 2;
  unsigned short* pW1 = (unsigned short*)(ws + off); off += (size_t)8 * 16 * 64 * 8 * 2;
  unsigned short* pW2 = (unsigned short*)(ws + off); off += (size_t)8 * 8 * 64 * 8 * 2;
  float* b1p = (float*)(ws + off); off += 1024;
  float* b2p = (float*)(ws + off); off += 512;
  float* woutp = (float*)(ws + off); off += 512;
  float* boutp = (float*)(ws + off); off += 256;
  float* stats = (float*)(ws + off); off += (size_t)NCOPY * 1280 * 4;
  unsigned short* tb = (unsigned short*)(ws + off); off += (size_t)17 * MAXR * 16 * 2;

  const int oS0 = 0, oQ0 = 256, oS1 = 512, oQ1 = 768, oS2 = 1024, oQ2 = 1152;

  k_prep0<<<64, 256, 0, stream>>>(W0, tables, pW0, tb, stats);
  k_gemm0<<<BR / 64, 256, 0, stream>>>(x, tb, pW0, b0, Y, stats, oS0, oQ0);
  k_fold<256, 256><<<32, 256, 0, stream>>>(stats, oS0, oQ0, g0, be0, W1, b1, pW1, b1p);
  k_gemm_mid<256, 4><<<BR / 64, 256, 0, stream>>>(Y, pW1, b1p, Y, stats, oS1, oQ1);
  k_fold<256, 128><<<32, 256, 0, stream>>>(stats, oS1, oQ1, g1, be1, W2, b2, pW2, b2p);
  k_gemm_mid<128, 2><<<BR / 64, 256, 0, stream>>>(Y, pW2, b2p, Y, stats, oS2, oQ2);
  k_foldout<<<1, 128, 0, stream>>>(stats, oS2, oQ2, g2, be2, Wout, bout, woutp, boutp);
  k_out<<<BR / 32, 256, 0, stream>>>(Y, woutp, boutp, out);
}